// Round 6
// baseline (342.466 us; speedup 1.0000x reference)
//
#include <hip/hip_runtime.h>
#include <hip/hip_cooperative_groups.h>
#include <stdint.h>

namespace cg = cooperative_groups;

#define NFEAT 4096
#define UI_PER_ROW (NFEAT / 4)
#define GRID 256
#define BLK 1024
#define ROWS_PB 32   /* rows per block in the cooperative path (8192/256) */

// 64 atomic slots for the fallback path, each on its own 64-byte line.
#define NSLOT 64
#define SLOT_STRIDE 16

// ---------------------------------------------------------------------------
// Exact emulation of the reference's LUT-based rounded integer sqrt.
// ---------------------------------------------------------------------------
__device__ __forceinline__ int isqrt_floor_small(int v) {
    int m = (int)sqrtf((float)v);
    m -= (m * m > v);
    m += ((m + 1) * (m + 1) <= v);
    return m;
}

__device__ __forceinline__ int sqrt_rounded_ref(int d) {
    if (d <= 0) return 0;
    int msb = 31 - __clz(d);
    int k = msb >> 1;
    int sh = (7 - k) * 2;
    int dn = d << sh;
    int la = (dn >> 8) & 255;
    int mant = isqrt_floor_small(la * 256 + 128);
    int qf = mant >> (7 - k);
    int bnd = qf * qf + qf;
    return (d > bnd) ? (qf + 1) : qf;
}

// Correctly-rounded x/s for uniform divisor s, rs = RN(1/s). Markstein fixup.
__device__ __forceinline__ float div_rn(float x, float s, float rs) {
    float q0 = x * rs;
    float r  = fmaf(-s, q0, x);
    return fmaf(r, rs, q0);
}

// Max of 256 plain slots; every lane of every wave returns the global max.
__device__ __forceinline__ float slots256_max(const unsigned* __restrict__ s, int lane) {
    unsigned v = s[lane];
    unsigned a = s[lane + 64], b = s[lane + 128], c = s[lane + 192];
    v = v > a ? v : a;
    v = v > b ? v : b;
    v = v > c ? v : c;
#pragma unroll
    for (int off = 32; off; off >>= 1) {
        unsigned o = (unsigned)__shfl_xor((int)v, off);
        v = v > o ? v : o;
    }
    return __uint_as_float(v);
}

// ===========================================================================
// Cooperative fused kernel: absmax -> gridsync -> rowstats(+ymax) -> gridsync
// -> requantize+write. x re-reads are L3-resident. No atomics anywhere.
// ===========================================================================
__global__ __launch_bounds__(BLK, 4) void fused_kernel(
    const float* __restrict__ x, const float* __restrict__ gamma,
    const float* __restrict__ beta, float* __restrict__ out,
    unsigned* __restrict__ slot, unsigned* __restrict__ slot2, int rows) {
#pragma clang fp contract(off)
    cg::grid_group gridg = cg::this_grid();
    const int bid = blockIdx.x;
    const int t = threadIdx.x;
    const int lane = t & 63;
    const int wave = t >> 6;

    __shared__ int a1s[16], a2s[16];
    __shared__ float redf[16];
    __shared__ float smu[ROWS_PB], sinv[ROWS_PB];

    // ---------------- phase 1: global absmax(x) ----------------
    {
        const float4* x4 = (const float4*)x;
        const int n4 = rows * (NFEAT / 4);
        const int stride = GRID * BLK;
        int i = bid * BLK + t;
        float m = 0.0f;
        for (; i + 3 * stride < n4; i += 4 * stride) {
            float4 a = x4[i];
            float4 b = x4[i + stride];
            float4 c = x4[i + 2 * stride];
            float4 d = x4[i + 3 * stride];
            float ma = fmaxf(fmaxf(fabsf(a.x), fabsf(a.y)), fmaxf(fabsf(a.z), fabsf(a.w)));
            float mb = fmaxf(fmaxf(fabsf(b.x), fabsf(b.y)), fmaxf(fabsf(b.z), fabsf(b.w)));
            float mc = fmaxf(fmaxf(fabsf(c.x), fabsf(c.y)), fmaxf(fabsf(c.z), fabsf(c.w)));
            float md = fmaxf(fmaxf(fabsf(d.x), fabsf(d.y)), fmaxf(fabsf(d.z), fabsf(d.w)));
            m = fmaxf(m, fmaxf(fmaxf(ma, mb), fmaxf(mc, md)));
        }
        for (; i < n4; i += stride) {
            float4 a = x4[i];
            m = fmaxf(m, fmaxf(fmaxf(fabsf(a.x), fabsf(a.y)), fmaxf(fabsf(a.z), fabsf(a.w))));
        }
#pragma unroll
        for (int off = 32; off; off >>= 1) m = fmaxf(m, __shfl_down(m, off));
        if (lane == 0) redf[wave] = m;
        __syncthreads();
        if (t == 0) {
            float mm = redf[0];
#pragma unroll
            for (int i2 = 1; i2 < 16; ++i2) mm = fmaxf(mm, redf[i2]);
            slot[bid] = __float_as_uint(mm);
        }
    }
    gridg.sync();

    // ---------------- phase 2: per-row stats + y absmax ----------------
    const float s  = fmaxf(slots256_max(slot, lane) / 127.0f, 1e-8f);
    const float rs = 1.0f / s;
    const int rb = t >> 8;     // row within 4-row batch
    const int tr = t & 255;    // thread within row
    const int nb = ROWS_PB / 4;
    float ym = 0.0f;
    for (int b = 0; b < nb; ++b) {
        const int r = bid * ROWS_PB + b * 4 + rb;
        const float4* xr = (const float4*)(x + (size_t)r * NFEAT);
        float4 v0 = xr[tr];
        float4 v1 = xr[256 + tr];
        float4 v2 = xr[512 + tr];
        float4 v3 = xr[768 + tr];
        float xv[16] = {v0.x, v0.y, v0.z, v0.w, v1.x, v1.y, v1.z, v1.w,
                        v2.x, v2.y, v2.z, v2.w, v3.x, v3.y, v3.z, v3.w};
        int xi[16];
        int s1 = 0, s2 = 0;
#pragma unroll
        for (int k = 0; k < 16; ++k) {
            float q = rintf(div_rn(xv[k], s, rs));
            q = fminf(fmaxf(q, -127.0f), 127.0f);
            int qi = (int)q;
            xi[k] = qi;
            s1 += qi;
            s2 += qi * qi;
        }
#pragma unroll
        for (int off = 32; off; off >>= 1) {
            s1 += __shfl_down(s1, off);
            s2 += __shfl_down(s2, off);
        }
        if (lane == 0) { a1s[wave] = s1; a2s[wave] = s2; }
        __syncthreads();
        if (tr == 0) {
            const int w0 = rb * 4;
            int Exi  = a1s[w0] + a1s[w0 + 1] + a1s[w0 + 2] + a1s[w0 + 3];
            int Ex2i = a2s[w0] + a2s[w0 + 1] + a2s[w0 + 2] + a2s[w0 + 3];
            float Ex  = (float)Exi * s;
            float Ex2 = (float)Ex2i * s * s;
            float mu  = Ex / (float)NFEAT;
            float var = fmaxf(Ex2 / (float)NFEAT - mu * mu, 0.0f);
            float vr  = fminf(fmaxf(rintf(var), 1.0f), 65535.0f);
            int std_int = sqrt_rounded_ref((int)vr);
            float inv = 1.0f / fmaxf((float)std_int, 1e-5f);
            smu[b * 4 + rb]  = mu;
            sinv[b * 4 + rb] = inv;
        }
        __syncthreads();
        const float mu = smu[b * 4 + rb], inv = sinv[b * 4 + rb];
#pragma unroll
        for (int g = 0; g < 4; ++g) {
            float4 gm = ((const float4*)gamma)[g * 256 + tr];
            float4 bt = ((const float4*)beta)[g * 256 + tr];
            float gv[4] = {gm.x, gm.y, gm.z, gm.w};
            float bv[4] = {bt.x, bt.y, bt.z, bt.w};
#pragma unroll
            for (int j = 0; j < 4; ++j) {
                float xq = (float)xi[g * 4 + j] * s;
                float xn = (xq - mu) * inv;
                float y = xn * gv[j] + bv[j];
                ym = fmaxf(ym, fabsf(y));
            }
        }
    }
#pragma unroll
    for (int off = 32; off; off >>= 1) ym = fmaxf(ym, __shfl_down(ym, off));
    if (lane == 0) redf[wave] = ym;
    __syncthreads();
    if (t == 0) {
        float mm = redf[0];
#pragma unroll
        for (int i2 = 1; i2 < 16; ++i2) mm = fmaxf(mm, redf[i2]);
        slot2[bid] = __float_as_uint(mm);
    }
    gridg.sync();

    // ---------------- phase 3: requantize + write ----------------
    const float so  = fmaxf(slots256_max(slot2, lane) / 127.0f, 1e-8f);
    const float rso = 1.0f / so;
    for (int b = 0; b < nb; ++b) {
        const int r = bid * ROWS_PB + b * 4 + rb;
        const float4* xr = (const float4*)(x + (size_t)r * NFEAT);
        float4 v0 = xr[tr];
        float4 v1 = xr[256 + tr];
        float4 v2 = xr[512 + tr];
        float4 v3 = xr[768 + tr];
        float xv[16] = {v0.x, v0.y, v0.z, v0.w, v1.x, v1.y, v1.z, v1.w,
                        v2.x, v2.y, v2.z, v2.w, v3.x, v3.y, v3.z, v3.w};
        const float mu = smu[b * 4 + rb], inv = sinv[b * 4 + rb];
        float4* outr = (float4*)(out + (size_t)r * NFEAT);
#pragma unroll
        for (int g = 0; g < 4; ++g) {
            float4 gm = ((const float4*)gamma)[g * 256 + tr];
            float4 bt = ((const float4*)beta)[g * 256 + tr];
            float gv[4] = {gm.x, gm.y, gm.z, gm.w};
            float bv[4] = {bt.x, bt.y, bt.z, bt.w};
            float o[4];
#pragma unroll
            for (int j = 0; j < 4; ++j) {
                float q = rintf(div_rn(xv[g * 4 + j], s, rs));  // == phase-2 value
                q = fminf(fmaxf(q, -127.0f), 127.0f);
                float xq = q * s;        // q integral -> identical to (float)(int)q * s
                float xn = (xq - mu) * inv;
                float y = xn * gv[j] + bv[j];
                float qq = rintf(div_rn(y, so, rso));
                qq = fminf(fmaxf(qq, -127.0f), 127.0f);
                o[j] = qq * so;
            }
            outr[g * 256 + tr] = make_float4(o[0], o[1], o[2], o[3]);
        }
    }
}

// ===========================================================================
// Fallback path (proven R2 kernels) — used if cooperative launch unavailable
// or rows != GRID*ROWS_PB.
// ===========================================================================
__device__ __forceinline__ float slot_max64(const unsigned* __restrict__ slots) {
    unsigned v = slots[(threadIdx.x & 63) * SLOT_STRIDE];
#pragma unroll
    for (int off = 32; off; off >>= 1) {
        unsigned o = (unsigned)__shfl_xor((int)v, off);
        v = v > o ? v : o;
    }
    return __uint_as_float(v);
}

__global__ __launch_bounds__(256, 4) void absmax_kernel(const float* __restrict__ x,
                                                        int n4,
                                                        unsigned* __restrict__ hx) {
    const float4* x4 = (const float4*)x;
    int i = blockIdx.x * 256 + threadIdx.x;
    const int stride = gridDim.x * 256;
    float m = 0.0f;
    for (; i + 3 * stride < n4; i += 4 * stride) {
        float4 a = x4[i];
        float4 b = x4[i + stride];
        float4 c = x4[i + 2 * stride];
        float4 d = x4[i + 3 * stride];
        float ma = fmaxf(fmaxf(fabsf(a.x), fabsf(a.y)), fmaxf(fabsf(a.z), fabsf(a.w)));
        float mb = fmaxf(fmaxf(fabsf(b.x), fabsf(b.y)), fmaxf(fabsf(b.z), fabsf(b.w)));
        float mc = fmaxf(fmaxf(fabsf(c.x), fabsf(c.y)), fmaxf(fabsf(c.z), fabsf(c.w)));
        float md = fmaxf(fmaxf(fabsf(d.x), fabsf(d.y)), fmaxf(fabsf(d.z), fabsf(d.w)));
        m = fmaxf(m, fmaxf(fmaxf(ma, mb), fmaxf(mc, md)));
    }
    for (; i < n4; i += stride) {
        float4 a = x4[i];
        m = fmaxf(m, fmaxf(fmaxf(fabsf(a.x), fabsf(a.y)), fmaxf(fabsf(a.z), fabsf(a.w))));
    }
#pragma unroll
    for (int off = 32; off; off >>= 1) m = fmaxf(m, __shfl_down(m, off));
    __shared__ float smax[4];
    int lane = threadIdx.x & 63, w = threadIdx.x >> 6;
    if (lane == 0) smax[w] = m;
    __syncthreads();
    if (threadIdx.x == 0) {
        m = fmaxf(fmaxf(smax[0], smax[1]), fmaxf(smax[2], smax[3]));
        atomicMax(hx + (blockIdx.x & (NSLOT - 1)) * SLOT_STRIDE, __float_as_uint(m));
    }
}

__global__ __launch_bounds__(256, 4) void rowstat_kernel(
    const float* __restrict__ x, const float* __restrict__ gamma,
    const float* __restrict__ beta, const unsigned* __restrict__ hx,
    unsigned* __restrict__ hy,
    float* __restrict__ row_mu, float* __restrict__ row_inv) {
#pragma clang fp contract(off)
    const int row = blockIdx.x;
    const int t = threadIdx.x;
    const float4* xr = (const float4*)(x + (size_t)row * NFEAT);
    float4 v0 = xr[t];
    float4 v1 = xr[256 + t];
    float4 v2 = xr[512 + t];
    float4 v3 = xr[768 + t];
    const float s  = fmaxf(slot_max64(hx) / 127.0f, 1e-8f);
    const float rs = 1.0f / s;

    float xv[16] = {v0.x, v0.y, v0.z, v0.w, v1.x, v1.y, v1.z, v1.w,
                    v2.x, v2.y, v2.z, v2.w, v3.x, v3.y, v3.z, v3.w};
    int xi[16];
    int s1 = 0, s2 = 0;
#pragma unroll
    for (int k = 0; k < 16; ++k) {
        float q = rintf(div_rn(xv[k], s, rs));
        q = fminf(fmaxf(q, -127.0f), 127.0f);
        int qi = (int)q;
        xi[k] = qi;
        s1 += qi;
        s2 += qi * qi;
    }
#pragma unroll
    for (int off = 32; off; off >>= 1) {
        s1 += __shfl_down(s1, off);
        s2 += __shfl_down(s2, off);
    }
    __shared__ int a1[4], a2[4];
    __shared__ float smu1, sinv1;
    const int lane = t & 63, w = t >> 6;
    if (lane == 0) { a1[w] = s1; a2[w] = s2; }
    __syncthreads();
    if (t == 0) {
        int Exi = a1[0] + a1[1] + a1[2] + a1[3];
        int Ex2i = a2[0] + a2[1] + a2[2] + a2[3];
        float Ex = (float)Exi * s;
        float Ex2 = (float)Ex2i * s * s;
        float mu = Ex / (float)NFEAT;
        float var = fmaxf(Ex2 / (float)NFEAT - mu * mu, 0.0f);
        float vr = fminf(fmaxf(rintf(var), 1.0f), 65535.0f);
        int std_int = sqrt_rounded_ref((int)vr);
        float inv_std = 1.0f / fmaxf((float)std_int, 1e-5f);
        row_mu[row] = mu;
        row_inv[row] = inv_std;
        smu1 = mu;
        sinv1 = inv_std;
    }
    __syncthreads();
    const float mu = smu1, inv = sinv1;
    float ym = 0.0f;
#pragma unroll
    for (int g = 0; g < 4; ++g) {
        float4 gm = ((const float4*)gamma)[g * 256 + t];
        float4 bt = ((const float4*)beta)[g * 256 + t];
        float gv[4] = {gm.x, gm.y, gm.z, gm.w};
        float bv[4] = {bt.x, bt.y, bt.z, bt.w};
#pragma unroll
        for (int j = 0; j < 4; ++j) {
            float xq = (float)xi[g * 4 + j] * s;
            float xn = (xq - mu) * inv;
            float y = xn * gv[j] + bv[j];
            ym = fmaxf(ym, fabsf(y));
        }
    }
#pragma unroll
    for (int off = 32; off; off >>= 1) ym = fmaxf(ym, __shfl_down(ym, off));
    __shared__ float aym[4];
    if (lane == 0) aym[w] = ym;
    __syncthreads();
    if (t == 0) {
        float m = fmaxf(fmaxf(aym[0], aym[1]), fmaxf(aym[2], aym[3]));
        atomicMax(hy + (row & (NSLOT - 1)) * SLOT_STRIDE, __float_as_uint(m));
    }
}

__global__ __launch_bounds__(256, 4) void quantout_f_kernel(
    const float* __restrict__ x, const float* __restrict__ gamma,
    const float* __restrict__ beta, const unsigned* __restrict__ hx,
    const unsigned* __restrict__ hy,
    const float* __restrict__ row_mu, const float* __restrict__ row_inv,
    float* __restrict__ out) {
#pragma clang fp contract(off)
    const int row = blockIdx.x;
    const int t = threadIdx.x;
    const float4* xr = (const float4*)(x + (size_t)row * NFEAT);
    float4 w0 = xr[t];
    float4 w1 = xr[256 + t];
    float4 w2 = xr[512 + t];
    float4 w3 = xr[768 + t];
    const float s_in  = fmaxf(slot_max64(hx) / 127.0f, 1e-8f);
    const float s_out = fmaxf(slot_max64(hy) / 127.0f, 1e-8f);
    const float rsi = 1.0f / s_in;
    const float rso = 1.0f / s_out;
    const float mu = row_mu[row], inv = row_inv[row];
    float4 vv[4] = {w0, w1, w2, w3};
    float4* outr = (float4*)(out + (size_t)row * NFEAT);
#pragma unroll
    for (int g = 0; g < 4; ++g) {
        float4 v = vv[g];
        float4 gm = ((const float4*)gamma)[g * 256 + t];
        float4 bt = ((const float4*)beta)[g * 256 + t];
        float xv[4] = {v.x, v.y, v.z, v.w};
        float gv[4] = {gm.x, gm.y, gm.z, gm.w};
        float bv[4] = {bt.x, bt.y, bt.z, bt.w};
        float o[4];
#pragma unroll
        for (int j = 0; j < 4; ++j) {
            float q = rintf(div_rn(xv[j], s_in, rsi));
            q = fminf(fmaxf(q, -127.0f), 127.0f);
            float xq = q * s_in;
            float xn = (xq - mu) * inv;
            float y = xn * gv[j] + bv[j];
            float qq = rintf(div_rn(y, s_out, rso));
            qq = fminf(fmaxf(qq, -127.0f), 127.0f);
            o[j] = qq * s_out;
        }
        outr[g * 256 + t] = make_float4(o[0], o[1], o[2], o[3]);
    }
}

extern "C" void kernel_launch(void* const* d_in, const int* in_sizes, int n_in,
                              void* d_out, int out_size, void* d_ws, size_t ws_size,
                              hipStream_t stream) {
    const float* x = (const float*)d_in[0];
    const float* gamma = (const float*)d_in[1];
    const float* beta = (const float*)d_in[2];
    float* out = (float*)d_out;

    const int total = in_sizes[0];
    int rows = total / NFEAT;

    char* ws = (char*)d_ws;
    unsigned* slot  = (unsigned*)ws;               // 256 * 4 B (coop phase 1)
    unsigned* slot2 = (unsigned*)(ws + 2048);      // 256 * 4 B (coop phase 2)

    if (rows == GRID * ROWS_PB) {
        void* args[] = {(void*)&x, (void*)&gamma, (void*)&beta, (void*)&out,
                        (void*)&slot, (void*)&slot2, (void*)&rows};
        hipError_t e = hipLaunchCooperativeKernel((void*)fused_kernel,
                                                  dim3(GRID), dim3(BLK),
                                                  args, 0, stream);
        if (e == hipSuccess) return;
    }

    // ---------------- fallback: proven 3-kernel path ----------------
    unsigned* hx = (unsigned*)ws;                  // 64 slots * 64 B
    unsigned* hy = (unsigned*)(ws + 4096);
    float* row_mu = (float*)(ws + 8192);
    float* row_inv = row_mu + rows;

    hipMemsetAsync(ws, 0, 8192, stream);
    absmax_kernel<<<2048, 256, 0, stream>>>(x, total / 4, hx);
    rowstat_kernel<<<rows, 256, 0, stream>>>(x, gamma, beta, hx, hy,
                                             row_mu, row_inv);
    quantout_f_kernel<<<rows, 256, 0, stream>>>(x, gamma, beta, hx, hy,
                                                row_mu, row_inv, out);
}